// Round 5
// baseline (143.640 us; speedup 1.0000x reference)
//
#include <hip/hip_runtime.h>
#include <hip/hip_bf16.h>
#include <math.h>

// Problem constants
#define B_    2
#define K_    8
#define C_    64
#define CH_   32      // C/2
#define H_    128
#define W_    128
#define HW_   16384   // H*W
#define BN_EPS 1e-5f
#define SIGMA_MAX 0.3f
#define COV_SHRINK 0.1f
#define COV_DELTA 1e-3f

// 32-way repeat macro: generates NAMED scalar accumulators so the compiler
// can never demote them to scratch (rounds 1-3 lesson: acc[32] arrays were
// dynamically indexed when the unroller gave up -> scratch-thrash, 47us;
// round 4's named scalars fixed it).
#define REP32(M) \
    M(0)  M(1)  M(2)  M(3)  M(4)  M(5)  M(6)  M(7)  \
    M(8)  M(9)  M(10) M(11) M(12) M(13) M(14) M(15) \
    M(16) M(17) M(18) M(19) M(20) M(21) M(22) M(23) \
    M(24) M(25) M(26) M(27) M(28) M(29) M(30) M(31)

// ---------------------------------------------------------------------------
// Kernel 0: fold BN into w1 and transpose to wf[c][o] (contiguous in o so
// stage1's weights are wave-uniform s_load_dwordx16 loads).
//   par[0..2047]  wf[c][o] = w1[o][c] * bn_scale[o]/sqrt(var[o]+eps)
//   par[2048+o]   beff[o]  = bn_bias[o] - bn_mean[o]*inv_std[o]
//   par[2080+o]   w2[o]
// ---------------------------------------------------------------------------
__global__ void prep_kernel(const float* __restrict__ w1,
                            const float* __restrict__ bn_scale,
                            const float* __restrict__ bn_bias,
                            const float* __restrict__ bn_mean,
                            const float* __restrict__ bn_var,
                            const float* __restrict__ w2,
                            float* __restrict__ par) {
    int t = threadIdx.x;
    for (int i = t; i < CH_ * C_; i += blockDim.x) {
        int c = i >> 5;         // 0..63
        int o = i & 31;         // 0..31
        float inv = bn_scale[o] * rsqrtf(bn_var[o] + BN_EPS);
        par[c * CH_ + o] = w1[o * C_ + c] * inv;
    }
    if (t < CH_) {
        float inv = bn_scale[t] * rsqrtf(bn_var[t] + BN_EPS);
        par[2048 + t] = bn_bias[t] - bn_mean[t] * inv;
        par[2080 + t] = w2[t];
    }
}

// ---------------------------------------------------------------------------
// Kernel 1: sensor maps. TWO pixels per thread (float2 coalesced X loads),
// 64 NAMED scalar accumulators (u0..u31 / v0..v31). Each weight s_load feeds
// two fmas -> halved scalar-load pressure and loop overhead vs round 4.
// 131072 threads -> 512 blocks, ~80 VGPR. VALU floor ~14us total.
// ---------------------------------------------------------------------------
__global__ void __launch_bounds__(256)
stage1_kernel(const float* __restrict__ X,
              const float* __restrict__ wf,    // [64][32] contiguous in o
              const float* __restrict__ beff,  // [32]
              const float* __restrict__ w2c,   // [32]
              float* __restrict__ S) {
    int t = blockIdx.x * blockDim.x + threadIdx.x;   // 0 .. B*K*HW/2-1
    int hw2 = t & (HW_ / 2 - 1);
    int bk  = t >> 13;
    const float2* xp = (const float2*)(X + (size_t)bk * (C_ * HW_)) + hw2;

#define DECL_ACC(o) float u##o = beff[o]; float v##o = u##o;
    REP32(DECL_ACC)
#undef DECL_ACC

#pragma unroll 4
    for (int c = 0; c < C_; ++c) {
        float2 xv = xp[(size_t)c * (HW_ / 2)];
        const float* wr = wf + c * CH_;        // wave-uniform -> s_load
#define FMA_ONE(o) u##o = fmaf(wr[o], xv.x, u##o); v##o = fmaf(wr[o], xv.y, v##o);
        REP32(FMA_ONE)
#undef FMA_ONE
    }

    float s0 = 0.f, s1 = 0.f;
#define REDUCE_ONE(o) \
    s0 = fmaf(w2c[o], fmaxf(u##o, 0.f), s0); \
    s1 = fmaf(w2c[o], fmaxf(v##o, 0.f), s1);
    REP32(REDUCE_ONE)
#undef REDUCE_ONE
    ((float2*)S)[t] = make_float2(s0, s1);
}

// ---------------------------------------------------------------------------
// Kernel 2: capon + fusion merged. One thread per pixel:
//   3x3 reflect patches -> 8x8 covariance -> Cholesky solve -> w[8]
//   then Y[b,c,hw] = sum_k w[k] * X[b,k,c,hw] for all 64 c (coalesced, NT).
// Saves the wW round-trip and one dispatch. block=64 -> 512 blocks cover all
// 256 CUs for both the latency-bound solve and the L3-read fusion phase.
// ---------------------------------------------------------------------------
__global__ void capon_fuse_kernel(const float* __restrict__ S,
                                  const float* __restrict__ a0_raw,    // [8]
                                  const float* __restrict__ sigma_raw, // [8]
                                  const float* __restrict__ X,
                                  float* __restrict__ out) {
    int idx = blockIdx.x * blockDim.x + threadIdx.x;  // 0 .. B*HW-1
    int b  = idx >> 14;
    int hw = idx & (HW_ - 1);
    int h  = hw >> 7;
    int w  = hw & (W_ - 1);

    // inline softmax / sigma^2 (uniform scalar math)
    float a0[K_], sig2[K_];
    {
        float m = -1e30f;
#pragma unroll
        for (int i = 0; i < K_; ++i) m = fmaxf(m, a0_raw[i]);
        float sum = 0.f;
#pragma unroll
        for (int i = 0; i < K_; ++i) { a0[i] = __expf(a0_raw[i] - m); sum += a0[i]; }
        float invs = 1.f / sum;
#pragma unroll
        for (int i = 0; i < K_; ++i) a0[i] *= invs;
#pragma unroll
        for (int i = 0; i < K_; ++i) {
            float sg = SIGMA_MAX / (1.f + __expf(-sigma_raw[i]));
            sig2[i] = sg * sg;
        }
    }

    // reflect padding (np.pad 'reflect': -1 -> 1, H -> H-2)
    int hm = (h == 0)      ? 1       : h - 1;
    int hp = (h == H_ - 1) ? H_ - 2  : h + 1;
    int wm = (w == 0)      ? 1       : w - 1;
    int wp = (w == W_ - 1) ? W_ - 2  : w + 1;
    int rows[3] = {hm * W_, h * W_, hp * W_};
    int cols[3] = {wm, w, wp};

    float pc[K_][9];
#pragma unroll
    for (int k = 0; k < K_; ++k) {
        const float* sp = S + (((size_t)b * K_ + k) << 14);
        float p[9];
        float m = 0.f;
#pragma unroll
        for (int i = 0; i < 3; ++i)
#pragma unroll
            for (int j = 0; j < 3; ++j) {
                float v = sp[rows[i] + cols[j]];
                p[i * 3 + j] = v;
                m += v;
            }
        m *= (1.f / 9.f);
#pragma unroll
        for (int n = 0; n < 9; ++n) pc[k][n] = p[n] - m;
    }

    // A = 0.9*R + (0.1*tr(R)/K + delta)*I + diag(sig2); R[i][j] = pc_i·pc_j / 9
    float A[K_][K_];
    float tr = 0.f;
#pragma unroll
    for (int i = 0; i < K_; ++i) {
        float s = 0.f;
#pragma unroll
        for (int n = 0; n < 9; ++n) s = fmaf(pc[i][n], pc[i][n], s);
        s *= (1.f / 9.f);
        tr += s;
        A[i][i] = s;
    }
#pragma unroll
    for (int i = 0; i < K_; ++i)
#pragma unroll
        for (int j = 0; j < i; ++j) {
            float s = 0.f;
#pragma unroll
            for (int n = 0; n < 9; ++n) s = fmaf(pc[i][n], pc[j][n], s);
            A[i][j] = (1.f - COV_SHRINK) * s * (1.f / 9.f);
        }
    float dl = COV_SHRINK * tr * (1.f / (float)K_) + COV_DELTA;
#pragma unroll
    for (int i = 0; i < K_; ++i)
        A[i][i] = (1.f - COV_SHRINK) * A[i][i] + dl + sig2[i];

    // Cholesky A = L L^T
#pragma unroll
    for (int j = 0; j < K_; ++j) {
        float d = A[j][j];
#pragma unroll
        for (int t = 0; t < j; ++t) d = fmaf(-A[j][t], A[j][t], d);
        d = sqrtf(d);
        A[j][j] = d;
        float inv = 1.f / d;
#pragma unroll
        for (int i = j + 1; i < K_; ++i) {
            float s = A[i][j];
#pragma unroll
            for (int t = 0; t < j; ++t) s = fmaf(-A[i][t], A[j][t], s);
            A[i][j] = s * inv;
        }
    }
    // forward solve L z = a0
    float z[K_];
#pragma unroll
    for (int i = 0; i < K_; ++i) {
        float s = a0[i];
#pragma unroll
        for (int t = 0; t < i; ++t) s = fmaf(-A[i][t], z[t], s);
        z[i] = s / A[i][i];
    }
    // back solve L^T x = z
    float x[K_];
#pragma unroll
    for (int i = K_ - 1; i >= 0; --i) {
        float s = z[i];
#pragma unroll
        for (int t = i + 1; t < K_; ++t) s = fmaf(-A[t][i], x[t], s);
        x[i] = s / A[i][i];
    }
    float denom = 0.f;
#pragma unroll
    for (int k = 0; k < K_; ++k) denom = fmaf(x[k], a0[k], denom);
    float invd = 1.f / denom;

    float wk[K_];
#pragma unroll
    for (int k = 0; k < K_; ++k) wk[k] = x[k] * invd;

    // ---- fusion: Y[b,c,hw] = sum_k wk[k] * X[b,k,c,hw] ----
    const float* xb = X + ((size_t)b * K_) * (C_ * HW_) + hw;
    float* ob = out + ((size_t)b * C_) * HW_ + hw;
    const size_t KS = (size_t)C_ * HW_;     // k stride

#pragma unroll 4
    for (int c = 0; c < C_; ++c) {
        const float* xc = xb + (size_t)c * HW_;
        float acc = wk[0] * xc[0];
        acc = fmaf(wk[1], xc[KS * 1], acc);
        acc = fmaf(wk[2], xc[KS * 2], acc);
        acc = fmaf(wk[3], xc[KS * 3], acc);
        acc = fmaf(wk[4], xc[KS * 4], acc);
        acc = fmaf(wk[5], xc[KS * 5], acc);
        acc = fmaf(wk[6], xc[KS * 6], acc);
        acc = fmaf(wk[7], xc[KS * 7], acc);
        __builtin_nontemporal_store(acc, ob + (size_t)c * HW_);
    }
}

// ---------------------------------------------------------------------------
extern "C" void kernel_launch(void* const* d_in, const int* in_sizes, int n_in,
                              void* d_out, int out_size, void* d_ws, size_t ws_size,
                              hipStream_t stream) {
    const float* X         = (const float*)d_in[0];
    const float* w1        = (const float*)d_in[1];
    const float* bn_scale  = (const float*)d_in[2];
    const float* bn_bias   = (const float*)d_in[3];
    const float* bn_mean   = (const float*)d_in[4];
    const float* bn_var    = (const float*)d_in[5];
    const float* w2        = (const float*)d_in[6];
    const float* a0_raw    = (const float*)d_in[7];
    const float* sigma_raw = (const float*)d_in[8];
    float* out = (float*)d_out;
    float* ws  = (float*)d_ws;

    float* par = ws;                         // 4096 floats (params)
    float* S   = ws + 4096;                  // B*K*HW = 262144 floats

    prep_kernel<<<1, 256, 0, stream>>>(w1, bn_scale, bn_bias, bn_mean, bn_var,
                                       w2, par);

    int n1 = B_ * K_ * HW_ / 2;              // 131072 threads (2 px each)
    stage1_kernel<<<n1 / 256, 256, 0, stream>>>(X, par, par + 2048, par + 2080, S);

    int n2 = B_ * HW_;                       // 32768
    capon_fuse_kernel<<<n2 / 64, 64, 0, stream>>>(S, a0_raw, sigma_raw, X, out);
}

// Round 6
// 143.006 us; speedup vs baseline: 1.0044x; 1.0044x over previous
//
#include <hip/hip_runtime.h>
#include <hip/hip_bf16.h>
#include <math.h>

// Problem constants
#define B_    2
#define K_    8
#define C_    64
#define CH_   32      // C/2
#define H_    128
#define W_    128
#define HW_   16384   // H*W
#define BN_EPS 1e-5f
#define SIGMA_MAX 0.3f
#define COV_SHRINK 0.1f
#define COV_DELTA 1e-3f

// 32-way repeat macro: NAMED scalar accumulators (arrays get demoted to
// scratch when the unroller gives up - rounds 1-3). ALSO learned (round 5):
// gfx950 allocates registers for 8-waves/SIMD occupancy = 64 VGPR budget;
// anything needing more gets spill code. So: exactly 32 accumulators.
#define REP32(M) \
    M(0)  M(1)  M(2)  M(3)  M(4)  M(5)  M(6)  M(7)  \
    M(8)  M(9)  M(10) M(11) M(12) M(13) M(14) M(15) \
    M(16) M(17) M(18) M(19) M(20) M(21) M(22) M(23) \
    M(24) M(25) M(26) M(27) M(28) M(29) M(30) M(31)

// ---------------------------------------------------------------------------
// Kernel 0: fold BN into w1 and transpose to wf[c][o] (contiguous in o so
// stage1's weights are wave-uniform s_load_dwordx16 loads).
//   par[0..2047]  wf[c][o] = w1[o][c] * bn_scale[o]/sqrt(var[o]+eps)
//   par[2048+o]   beff[o]  = bn_bias[o] - bn_mean[o]*inv_std[o]
//   par[2080+o]   w2[o]
// ---------------------------------------------------------------------------
__global__ void prep_kernel(const float* __restrict__ w1,
                            const float* __restrict__ bn_scale,
                            const float* __restrict__ bn_bias,
                            const float* __restrict__ bn_mean,
                            const float* __restrict__ bn_var,
                            const float* __restrict__ w2,
                            float* __restrict__ par) {
    int t = threadIdx.x;
    for (int i = t; i < CH_ * C_; i += blockDim.x) {
        int c = i >> 5;         // 0..63
        int o = i & 31;         // 0..31
        float inv = bn_scale[o] * rsqrtf(bn_var[o] + BN_EPS);
        par[c * CH_ + o] = w1[o * C_ + c] * inv;
    }
    if (t < CH_) {
        float inv = bn_scale[t] * rsqrtf(bn_var[t] + BN_EPS);
        par[2048 + t] = bn_bias[t] - bn_mean[t] * inv;
        par[2080 + t] = w2[t];
    }
}

// ---------------------------------------------------------------------------
// Kernel 1: sensor maps. ONE pixel per thread (fits the 64-VGPR occupancy
// budget: 32 named accs + 8 x-temps + addressing ~= 52-60 VGPR, no spill).
// c-loop steps by 4 with 4 explicit loads issued before the 128 FMAs;
// unroll 2 -> 8 loads in flight per wave (32 B/lane) so HBM latency
// (~900 cyc) is hidden at 16 waves/CU: 16*64*32B = 32 KB/CU in flight
// vs ~9.2 KB needed for 6.3 TB/s.
// ---------------------------------------------------------------------------
__global__ void __launch_bounds__(256)
stage1_kernel(const float* __restrict__ X,
              const float* __restrict__ wf,    // [64][32] contiguous in o
              const float* __restrict__ beff,  // [32]
              const float* __restrict__ w2c,   // [32]
              float* __restrict__ S) {
    int idx = blockIdx.x * blockDim.x + threadIdx.x;   // 0 .. B*K*HW-1
    int hw = idx & (HW_ - 1);
    int bk = idx >> 14;
    const float* xp = X + (size_t)bk * (C_ * HW_) + hw;

#define DECL_ACC(o) float a##o = beff[o];
    REP32(DECL_ACC)
#undef DECL_ACC

#pragma unroll 2
    for (int c = 0; c < C_; c += 4) {
        float x0 = xp[(size_t)(c + 0) * HW_];
        float x1 = xp[(size_t)(c + 1) * HW_];
        float x2 = xp[(size_t)(c + 2) * HW_];
        float x3 = xp[(size_t)(c + 3) * HW_];
        const float* w0r = wf + (c + 0) * CH_;   // wave-uniform -> s_load
        const float* w1r = wf + (c + 1) * CH_;
        const float* w2r = wf + (c + 2) * CH_;
        const float* w3r = wf + (c + 3) * CH_;
#define FMA4(o) \
        a##o = fmaf(w0r[o], x0, a##o); \
        a##o = fmaf(w1r[o], x1, a##o); \
        a##o = fmaf(w2r[o], x2, a##o); \
        a##o = fmaf(w3r[o], x3, a##o);
        REP32(FMA4)
#undef FMA4
    }

    float s = 0.f;
#define REDUCE_ONE(o) s = fmaf(w2c[o], fmaxf(a##o, 0.f), s);
    REP32(REDUCE_ONE)
#undef REDUCE_ONE
    S[idx] = s;
}

// ---------------------------------------------------------------------------
// Kernel 2: capon + fusion merged. One thread per pixel:
//   3x3 reflect patches -> 8x8 covariance -> Cholesky solve -> w[8]
//   then Y[b,c,hw] = sum_k w[k] * X[b,k,c,hw] for all 64 c (coalesced, NT).
// block=64 -> 512 blocks cover all 256 CUs for the latency-bound solve;
// fusion reads are L3-hits (X just swept by stage1).
// ---------------------------------------------------------------------------
__global__ void capon_fuse_kernel(const float* __restrict__ S,
                                  const float* __restrict__ a0_raw,    // [8]
                                  const float* __restrict__ sigma_raw, // [8]
                                  const float* __restrict__ X,
                                  float* __restrict__ out) {
    int idx = blockIdx.x * blockDim.x + threadIdx.x;  // 0 .. B*HW-1
    int b  = idx >> 14;
    int hw = idx & (HW_ - 1);
    int h  = hw >> 7;
    int w  = hw & (W_ - 1);

    // inline softmax / sigma^2 (uniform scalar math)
    float a0[K_], sig2[K_];
    {
        float m = -1e30f;
#pragma unroll
        for (int i = 0; i < K_; ++i) m = fmaxf(m, a0_raw[i]);
        float sum = 0.f;
#pragma unroll
        for (int i = 0; i < K_; ++i) { a0[i] = __expf(a0_raw[i] - m); sum += a0[i]; }
        float invs = 1.f / sum;
#pragma unroll
        for (int i = 0; i < K_; ++i) a0[i] *= invs;
#pragma unroll
        for (int i = 0; i < K_; ++i) {
            float sg = SIGMA_MAX / (1.f + __expf(-sigma_raw[i]));
            sig2[i] = sg * sg;
        }
    }

    // reflect padding (np.pad 'reflect': -1 -> 1, H -> H-2)
    int hm = (h == 0)      ? 1       : h - 1;
    int hp = (h == H_ - 1) ? H_ - 2  : h + 1;
    int wm = (w == 0)      ? 1       : w - 1;
    int wp = (w == W_ - 1) ? W_ - 2  : w + 1;
    int rows[3] = {hm * W_, h * W_, hp * W_};
    int cols[3] = {wm, w, wp};

    float pc[K_][9];
#pragma unroll
    for (int k = 0; k < K_; ++k) {
        const float* sp = S + (((size_t)b * K_ + k) << 14);
        float p[9];
        float m = 0.f;
#pragma unroll
        for (int i = 0; i < 3; ++i)
#pragma unroll
            for (int j = 0; j < 3; ++j) {
                float v = sp[rows[i] + cols[j]];
                p[i * 3 + j] = v;
                m += v;
            }
        m *= (1.f / 9.f);
#pragma unroll
        for (int n = 0; n < 9; ++n) pc[k][n] = p[n] - m;
    }

    // A = 0.9*R + (0.1*tr(R)/K + delta)*I + diag(sig2); R[i][j] = pc_i·pc_j / 9
    float A[K_][K_];
    float tr = 0.f;
#pragma unroll
    for (int i = 0; i < K_; ++i) {
        float s = 0.f;
#pragma unroll
        for (int n = 0; n < 9; ++n) s = fmaf(pc[i][n], pc[i][n], s);
        s *= (1.f / 9.f);
        tr += s;
        A[i][i] = s;
    }
#pragma unroll
    for (int i = 0; i < K_; ++i)
#pragma unroll
        for (int j = 0; j < i; ++j) {
            float s = 0.f;
#pragma unroll
            for (int n = 0; n < 9; ++n) s = fmaf(pc[i][n], pc[j][n], s);
            A[i][j] = (1.f - COV_SHRINK) * s * (1.f / 9.f);
        }
    float dl = COV_SHRINK * tr * (1.f / (float)K_) + COV_DELTA;
#pragma unroll
    for (int i = 0; i < K_; ++i)
        A[i][i] = (1.f - COV_SHRINK) * A[i][i] + dl + sig2[i];

    // Cholesky A = L L^T
#pragma unroll
    for (int j = 0; j < K_; ++j) {
        float d = A[j][j];
#pragma unroll
        for (int t = 0; t < j; ++t) d = fmaf(-A[j][t], A[j][t], d);
        d = sqrtf(d);
        A[j][j] = d;
        float inv = 1.f / d;
#pragma unroll
        for (int i = j + 1; i < K_; ++i) {
            float s = A[i][j];
#pragma unroll
            for (int t = 0; t < j; ++t) s = fmaf(-A[i][t], A[j][t], s);
            A[i][j] = s * inv;
        }
    }
    // forward solve L z = a0
    float z[K_];
#pragma unroll
    for (int i = 0; i < K_; ++i) {
        float s = a0[i];
#pragma unroll
        for (int t = 0; t < i; ++t) s = fmaf(-A[i][t], z[t], s);
        z[i] = s / A[i][i];
    }
    // back solve L^T x = z
    float x[K_];
#pragma unroll
    for (int i = K_ - 1; i >= 0; --i) {
        float s = z[i];
#pragma unroll
        for (int t = i + 1; t < K_; ++t) s = fmaf(-A[t][i], x[t], s);
        x[i] = s / A[i][i];
    }
    float denom = 0.f;
#pragma unroll
    for (int k = 0; k < K_; ++k) denom = fmaf(x[k], a0[k], denom);
    float invd = 1.f / denom;

    float wk[K_];
#pragma unroll
    for (int k = 0; k < K_; ++k) wk[k] = x[k] * invd;

    // ---- fusion: Y[b,c,hw] = sum_k wk[k] * X[b,k,c,hw] ----
    const float* xb = X + ((size_t)b * K_) * (C_ * HW_) + hw;
    float* ob = out + ((size_t)b * C_) * HW_ + hw;
    const size_t KS = (size_t)C_ * HW_;     // k stride

#pragma unroll 4
    for (int c = 0; c < C_; ++c) {
        const float* xc = xb + (size_t)c * HW_;
        float acc = wk[0] * xc[0];
        acc = fmaf(wk[1], xc[KS * 1], acc);
        acc = fmaf(wk[2], xc[KS * 2], acc);
        acc = fmaf(wk[3], xc[KS * 3], acc);
        acc = fmaf(wk[4], xc[KS * 4], acc);
        acc = fmaf(wk[5], xc[KS * 5], acc);
        acc = fmaf(wk[6], xc[KS * 6], acc);
        acc = fmaf(wk[7], xc[KS * 7], acc);
        __builtin_nontemporal_store(acc, ob + (size_t)c * HW_);
    }
}

// ---------------------------------------------------------------------------
extern "C" void kernel_launch(void* const* d_in, const int* in_sizes, int n_in,
                              void* d_out, int out_size, void* d_ws, size_t ws_size,
                              hipStream_t stream) {
    const float* X         = (const float*)d_in[0];
    const float* w1        = (const float*)d_in[1];
    const float* bn_scale  = (const float*)d_in[2];
    const float* bn_bias   = (const float*)d_in[3];
    const float* bn_mean   = (const float*)d_in[4];
    const float* bn_var    = (const float*)d_in[5];
    const float* w2        = (const float*)d_in[6];
    const float* a0_raw    = (const float*)d_in[7];
    const float* sigma_raw = (const float*)d_in[8];
    float* out = (float*)d_out;
    float* ws  = (float*)d_ws;

    float* par = ws;                         // 4096 floats (params)
    float* S   = ws + 4096;                  // B*K*HW = 262144 floats

    prep_kernel<<<1, 256, 0, stream>>>(w1, bn_scale, bn_bias, bn_mean, bn_var,
                                       w2, par);

    int n1 = B_ * K_ * HW_;                  // 262144 threads (1 px each)
    stage1_kernel<<<n1 / 256, 256, 0, stream>>>(X, par, par + 2048, par + 2080, S);

    int n2 = B_ * HW_;                       // 32768
    capon_fuse_kernel<<<n2 / 64, 64, 0, stream>>>(S, a0_raw, sigma_raw, X, out);
}